// Round 1
// baseline (1546.297 us; speedup 1.0000x reference)
//
#include <hip/hip_runtime.h>

#define EPS 1e-5f

constexpr int FIN = 22;   // input feature dim
constexpr int H   = 128;  // hidden dim

// ---------------- degree / norm ----------------
__global__ void deg_kernel(const int* __restrict__ ei, float* __restrict__ deg, int E) {
    int e = blockIdx.x * blockDim.x + threadIdx.x;
    if (e < E) atomicAdd(&deg[ei[E + e]], 1.0f);
}

__global__ void dinv_kernel(float* __restrict__ deg, int N) {
    int i = blockIdx.x * blockDim.x + threadIdx.x;
    if (i < N) deg[i] = rsqrtf(deg[i] + 1.0f);  // +1 self-loop; always > 0
}

// ---------------- layer-1: aggregate raw x (22 feats) ----------------
// xa[i] = x[i]*dinv[i]^2  (self-loop init)
__global__ void xa_init_kernel(const float* __restrict__ x, const float* __restrict__ dinv,
                               float* __restrict__ xa, int N) {
    int t = blockIdx.x * blockDim.x + threadIdx.x;
    int i = t >> 5, k = t & 31;
    if (i < N && k < FIN) {
        float d = dinv[i];
        xa[i * FIN + k] = x[i * FIN + k] * d * d;
    }
}

__global__ void scatter_x_kernel(const int* __restrict__ ei, const float* __restrict__ x,
                                 const float* __restrict__ dinv, float* __restrict__ xa, int E) {
    int t = blockIdx.x * blockDim.x + threadIdx.x;
    int e = t >> 5, k = t & 31;
    if (e >= E || k >= FIN) return;
    int s = ei[e], d = ei[E + e];
    float nrm = dinv[s] * dinv[d];
    atomicAdd(&xa[d * FIN + k], x[s * FIN + k] * nrm);
}

// ---------------- tiled small-N GEMM: [N,K] @ [K,128] ----------------
// 256 threads, 16 rows/block, 8 rows per thread (f = tid&127, row-group = tid>>7).
// BN_IN: apply folded BN(+bias)+ReLU to input rows while staging to LDS.
// DUAL:  also write out_agg = acc*dinv^2 (self-loop init for next aggregation).
template <int K, bool BN_IN, bool DUAL>
__global__ __launch_bounds__(256) void gemm_kernel(
    const float* __restrict__ in, const float* __restrict__ W,
    float* __restrict__ outh, float* __restrict__ outagg,
    const float* __restrict__ dinv,
    const float* __restrict__ bnb, const float* __restrict__ bnmean,
    const float* __restrict__ bnvar, const float* __restrict__ bngamma,
    const float* __restrict__ bnbeta) {
    __shared__ float lds[16 * K];
    const int tid = threadIdx.x;
    const int m0  = blockIdx.x * 16;

    for (int idx = tid; idx < 16 * K; idx += 256) {
        float v = in[m0 * K + idx];
        if (BN_IN) {
            int k = idx % K;
            float A = bngamma[k] * rsqrtf(bnvar[k] + EPS);
            float B = (bnb[k] - bnmean[k]) * A + bnbeta[k];
            v = fmaxf(v * A + B, 0.0f);
        }
        lds[idx] = v;
    }
    __syncthreads();

    const int f  = tid & 127;
    const int mg = tid >> 7;
    float acc[8];
#pragma unroll
    for (int j = 0; j < 8; ++j) acc[j] = 0.0f;

    for (int k = 0; k < K; ++k) {
        float w = W[k * H + f];
#pragma unroll
        for (int j = 0; j < 8; ++j)
            acc[j] += lds[(mg * 8 + j) * K + k] * w;  // LDS broadcast per wave
    }

#pragma unroll
    for (int j = 0; j < 8; ++j) {
        int node = m0 + mg * 8 + j;
        outh[node * H + f] = acc[j];
        if (DUAL) {
            float d = dinv[node];
            outagg[node * H + f] = acc[j] * d * d;
        }
    }
}

// ---------------- layer-2 scatter: 128-wide, float4 gather + 4 atomics ----------------
__global__ void scatter_h_kernel(const int* __restrict__ ei, const float* __restrict__ h,
                                 const float* __restrict__ dinv, float* __restrict__ agg, int E) {
    int t = blockIdx.x * blockDim.x + threadIdx.x;
    int e = t >> 5;
    if (e >= E) return;
    int f = (t & 31) * 4;
    int s = ei[e], d = ei[E + e];
    float nrm = dinv[s] * dinv[d];
    const float4 v = *reinterpret_cast<const float4*>(h + s * H + f);
    float* base = agg + d * H + f;
    atomicAdd(base + 0, v.x * nrm);
    atomicAdd(base + 1, v.y * nrm);
    atomicAdd(base + 2, v.z * nrm);
    atomicAdd(base + 3, v.w * nrm);
}

// ---------------- final: BN2(+b2)+ReLU, dot Wfc, +bfc, sigmoid ----------------
__global__ void final_kernel(const float* __restrict__ agg,
                             const float* __restrict__ b2, const float* __restrict__ mean2,
                             const float* __restrict__ var2, const float* __restrict__ gamma2,
                             const float* __restrict__ beta2, const float* __restrict__ Wfc,
                             const float* __restrict__ bfc, float* __restrict__ out, int N) {
    int t = blockIdx.x * blockDim.x + threadIdx.x;
    int node = t >> 6, lane = t & 63;
    if (node >= N) return;
    float p = 0.0f;
#pragma unroll
    for (int half = 0; half < 2; ++half) {
        int k = lane + half * 64;
        float A = gamma2[k] * rsqrtf(var2[k] + EPS);
        float B = (b2[k] - mean2[k]) * A + beta2[k];
        float v = agg[node * H + k];
        v = fmaxf(v * A + B, 0.0f);
        p += v * Wfc[k];
    }
#pragma unroll
    for (int off = 32; off > 0; off >>= 1) p += __shfl_down(p, off);
    if (lane == 0) out[node] = 1.0f / (1.0f + expf(-(p + bfc[0])));
}

extern "C" void kernel_launch(void* const* d_in, const int* in_sizes, int n_in,
                              void* d_out, int out_size, void* d_ws, size_t ws_size,
                              hipStream_t stream) {
    const float* x      = (const float*)d_in[0];
    const int*   ei     = (const int*)d_in[1];
    const float* W1     = (const float*)d_in[2];
    const float* b1     = (const float*)d_in[3];
    const float* gamma1 = (const float*)d_in[4];
    const float* beta1  = (const float*)d_in[5];
    const float* mean1  = (const float*)d_in[6];
    const float* var1   = (const float*)d_in[7];
    const float* W2     = (const float*)d_in[8];
    const float* b2     = (const float*)d_in[9];
    const float* gamma2 = (const float*)d_in[10];
    const float* beta2  = (const float*)d_in[11];
    const float* mean2  = (const float*)d_in[12];
    const float* var2   = (const float*)d_in[13];
    const float* Wfc    = (const float*)d_in[14];
    const float* bfc    = (const float*)d_in[15];
    float* out = (float*)d_out;

    const int N = in_sizes[0] / FIN;   // 50000
    const int E = in_sizes[1] / 2;     // 800000

    float* ws   = (float*)d_ws;
    float* dinv = ws;                            // N
    float* xa   = dinv + N;                      // N*22
    float* bufA = xa + (size_t)N * FIN;          // N*128  (h2)
    float* bufB = bufA + (size_t)N * H;          // N*128  (g1 / agg2)

    hipMemsetAsync(dinv, 0, (size_t)N * sizeof(float), stream);

    deg_kernel<<<(E + 255) / 256, 256, 0, stream>>>(ei, dinv, E);
    dinv_kernel<<<(N + 255) / 256, 256, 0, stream>>>(dinv, N);

    // layer 1: aggregate raw x, then GEMM -> g1 (pre-BN) in bufB
    xa_init_kernel<<<((size_t)N * 32 + 255) / 256, 256, 0, stream>>>(x, dinv, xa, N);
    scatter_x_kernel<<<((size_t)E * 32 + 255) / 256, 256, 0, stream>>>(ei, x, dinv, xa, E);
    gemm_kernel<FIN, false, false><<<N / 16, 256, 0, stream>>>(
        xa, W1, bufB, nullptr, nullptr, nullptr, nullptr, nullptr, nullptr, nullptr);

    // layer 2: BN1+ReLU fused into row staging; write h2 (bufA) + self-loop init (bufB)
    gemm_kernel<H, true, true><<<N / 16, 256, 0, stream>>>(
        bufB, W2, bufA, bufB, dinv, b1, mean1, var1, gamma1, beta1);
    scatter_h_kernel<<<((size_t)E * 32 + 255) / 256, 256, 0, stream>>>(ei, bufA, dinv, bufB, E);

    // BN2+ReLU + FC + sigmoid
    final_kernel<<<((size_t)N * 64 + 255) / 256, 256, 0, stream>>>(
        bufB, b2, mean2, var2, gamma2, beta2, Wfc, bfc, out, N);
}

// Round 2
// 370.519 us; speedup vs baseline: 4.1733x; 4.1733x over previous
//
#include <hip/hip_runtime.h>

#define EPS 1e-5f

constexpr int FIN = 22;   // input feature dim
constexpr int H   = 128;  // hidden dim

// ---------------- degree histogram (int) ----------------
__global__ void deg_kernel(const int* __restrict__ ei, int* __restrict__ degi, int E) {
    int e = blockIdx.x * blockDim.x + threadIdx.x;
    if (e < E) atomicAdd(&degi[ei[E + e]], 1);
}

__global__ void dinv_kernel(const int* __restrict__ degi, float* __restrict__ dinv, int N) {
    int i = blockIdx.x * blockDim.x + threadIdx.x;
    if (i < N) dinv[i] = rsqrtf((float)degi[i] + 1.0f);  // +1 self-loop
}

// ---------------- single-block chunked exclusive scan ----------------
__global__ __launch_bounds__(256) void scan_kernel(const int* __restrict__ degi,
                                                   int* __restrict__ offs, int N) {
    __shared__ int tsum[256];
    const int tid = threadIdx.x;
    const int per = (N + 255) / 256;
    const int start = tid * per;
    const int end = min(start + per, N);
    int s = 0;
    for (int i = start; i < end; ++i) s += degi[i];
    tsum[tid] = s;
    __syncthreads();
    if (tid == 0) {
        int run = 0;
        for (int i = 0; i < 256; ++i) { int t = tsum[i]; tsum[i] = run; run += t; }
    }
    __syncthreads();
    int base = tsum[tid];
    for (int i = start; i < end; ++i) { offs[i] = base; base += degi[i]; }
}

// ---------------- CSR fill; offs[d] shifts to end-of-range ----------------
__global__ void fill_kernel(const int* __restrict__ ei, const float* __restrict__ dinv,
                            int* __restrict__ offs, int* __restrict__ csrS,
                            float* __restrict__ csrN, int E) {
    int e = blockIdx.x * blockDim.x + threadIdx.x;
    if (e >= E) return;
    int s = ei[e], d = ei[E + e];
    int pos = atomicAdd(&offs[d], 1);
    csrS[pos] = s;
    csrN[pos] = dinv[s] * dinv[d];
}
// after fill: range of node d = [ d ? offs[d-1] : 0,  offs[d] )

// ---------------- layer-1 gather on raw x (22 feats) ----------------
__global__ void gather_x_kernel(const float* __restrict__ x, const float* __restrict__ dinv,
                                const int* __restrict__ offs, const int* __restrict__ csrS,
                                const float* __restrict__ csrN, float* __restrict__ xa, int N) {
    int t = blockIdx.x * blockDim.x + threadIdx.x;
    int node = t >> 5, k = t & 31;
    if (node >= N) return;
    int beg = node ? offs[node - 1] : 0;
    int end = offs[node];
    float di = dinv[node];
    float acc = 0.0f;
    if (k < FIN) acc = x[node * FIN + k] * di * di;  // self-loop
    for (int e = beg; e < end; ++e) {
        int s = csrS[e];
        float w = csrN[e];
        if (k < FIN) acc += x[s * FIN + k] * w;
    }
    if (k < FIN) xa[node * FIN + k] = acc;
}

// ---------------- tiled GEMM: [N,K] @ [K,128], optional fused BN+ReLU on input ----------------
template <int K, bool BN_IN>
__global__ __launch_bounds__(256) void gemm_kernel(
    const float* __restrict__ in, const float* __restrict__ W, float* __restrict__ outh,
    const float* __restrict__ bnb, const float* __restrict__ bnmean,
    const float* __restrict__ bnvar, const float* __restrict__ bngamma,
    const float* __restrict__ bnbeta) {
    __shared__ float lds[16 * K];
    const int tid = threadIdx.x;
    const int m0  = blockIdx.x * 16;

    for (int idx = tid; idx < 16 * K; idx += 256) {
        float v = in[m0 * K + idx];
        if (BN_IN) {
            int k = idx % K;
            float A = bngamma[k] * rsqrtf(bnvar[k] + EPS);
            float B = (bnb[k] - bnmean[k]) * A + bnbeta[k];
            v = fmaxf(v * A + B, 0.0f);
        }
        lds[idx] = v;
    }
    __syncthreads();

    const int f  = tid & 127;
    const int mg = tid >> 7;
    float acc[8];
#pragma unroll
    for (int j = 0; j < 8; ++j) acc[j] = 0.0f;

    for (int k = 0; k < K; ++k) {
        float w = W[k * H + f];
#pragma unroll
        for (int j = 0; j < 8; ++j)
            acc[j] += lds[(mg * 8 + j) * K + k] * w;
    }

#pragma unroll
    for (int j = 0; j < 8; ++j) outh[(m0 + mg * 8 + j) * H + f] = acc[j];
}

// ---------------- fused: layer-2 gather + BN2 + ReLU + FC + sigmoid ----------------
// one wave per node, float2 (2 feats) per lane; 4 nodes per 256-thread block
__global__ __launch_bounds__(256) void gfinal_kernel(
    const float* __restrict__ h2, const float* __restrict__ dinv,
    const int* __restrict__ offs, const int* __restrict__ csrS, const float* __restrict__ csrN,
    const float* __restrict__ b2, const float* __restrict__ mean2,
    const float* __restrict__ var2, const float* __restrict__ gamma2,
    const float* __restrict__ beta2, const float* __restrict__ Wfc,
    const float* __restrict__ bfc, float* __restrict__ out, int N) {
    const int tid  = threadIdx.x;
    const int node = blockIdx.x * 4 + (tid >> 6);
    const int lane = tid & 63;
    if (node >= N) return;
    const int beg = node ? offs[node - 1] : 0;
    const int end = offs[node];
    const float di = dinv[node];
    const float2* h2v = reinterpret_cast<const float2*>(h2);

    float2 self = h2v[(size_t)node * 64 + lane];
    float a0 = self.x * di * di;
    float a1 = self.y * di * di;
    for (int e = beg; e < end; ++e) {
        int s = csrS[e];
        float w = csrN[e];
        float2 hv = h2v[(size_t)s * 64 + lane];
        a0 += hv.x * w;
        a1 += hv.y * w;
    }
    const int f0 = lane * 2, f1 = f0 + 1;
    float A0 = gamma2[f0] * rsqrtf(var2[f0] + EPS);
    float B0 = (b2[f0] - mean2[f0]) * A0 + beta2[f0];
    float A1 = gamma2[f1] * rsqrtf(var2[f1] + EPS);
    float B1 = (b2[f1] - mean2[f1]) * A1 + beta2[f1];
    float v0 = fmaxf(a0 * A0 + B0, 0.0f);
    float v1 = fmaxf(a1 * A1 + B1, 0.0f);
    float p = v0 * Wfc[f0] + v1 * Wfc[f1];
#pragma unroll
    for (int off = 32; off > 0; off >>= 1) p += __shfl_down(p, off);
    if (lane == 0) out[node] = 1.0f / (1.0f + expf(-(p + bfc[0])));
}

extern "C" void kernel_launch(void* const* d_in, const int* in_sizes, int n_in,
                              void* d_out, int out_size, void* d_ws, size_t ws_size,
                              hipStream_t stream) {
    const float* x      = (const float*)d_in[0];
    const int*   ei     = (const int*)d_in[1];
    const float* W1     = (const float*)d_in[2];
    const float* b1     = (const float*)d_in[3];
    const float* gamma1 = (const float*)d_in[4];
    const float* beta1  = (const float*)d_in[5];
    const float* mean1  = (const float*)d_in[6];
    const float* var1   = (const float*)d_in[7];
    const float* W2     = (const float*)d_in[8];
    const float* b2     = (const float*)d_in[9];
    const float* gamma2 = (const float*)d_in[10];
    const float* beta2  = (const float*)d_in[11];
    const float* mean2  = (const float*)d_in[12];
    const float* var2   = (const float*)d_in[13];
    const float* Wfc    = (const float*)d_in[14];
    const float* bfc    = (const float*)d_in[15];
    float* out = (float*)d_out;

    const int N = in_sizes[0] / FIN;   // 50000
    const int E = in_sizes[1] / 2;     // 800000

    // workspace layout (4-byte units)
    char* wsb = (char*)d_ws;
    int*   degi = (int*)wsb;                               // N
    float* dinv = (float*)(wsb) + N;                       // N
    int*   offs = (int*)(wsb) + 2 * (size_t)N;             // N+1
    size_t csr_off = ((2 * (size_t)N + N + 1 + 15) / 16) * 16;  // align
    int*   csrS = (int*)(wsb) + csr_off;                   // E
    float* csrN = (float*)(wsb) + csr_off + E;             // E
    float* xa   = (float*)(wsb) + csr_off + 2 * (size_t)E;         // N*22
    float* bufA = xa + (size_t)N * FIN;                    // N*128 (h2)
    float* bufB = bufA + (size_t)N * H;                    // N*128 (g1)

    hipMemsetAsync(degi, 0, (size_t)N * sizeof(int), stream);

    deg_kernel<<<(E + 255) / 256, 256, 0, stream>>>(ei, degi, E);
    dinv_kernel<<<(N + 255) / 256, 256, 0, stream>>>(degi, dinv, N);
    scan_kernel<<<1, 256, 0, stream>>>(degi, offs, N);
    fill_kernel<<<(E + 255) / 256, 256, 0, stream>>>(ei, dinv, offs, csrS, csrN, E);

    // layer 1: gather raw x, GEMM -> g1 (pre-BN) in bufB
    gather_x_kernel<<<((size_t)N * 32 + 255) / 256, 256, 0, stream>>>(
        x, dinv, offs, csrS, csrN, xa, N);
    gemm_kernel<FIN, false><<<N / 16, 256, 0, stream>>>(
        xa, W1, bufB, nullptr, nullptr, nullptr, nullptr, nullptr);

    // layer 2: BN1+ReLU fused into staging; h2 -> bufA
    gemm_kernel<H, true><<<N / 16, 256, 0, stream>>>(
        bufB, W2, bufA, b1, mean1, var1, gamma1, beta1);

    // fused gather + BN2 + ReLU + FC + sigmoid
    gfinal_kernel<<<(N + 3) / 4, 256, 0, stream>>>(
        bufA, dinv, offs, csrS, csrN, b2, mean2, var2, gamma2, beta2, Wfc, bfc, out, N);
}

// Round 3
// 285.447 us; speedup vs baseline: 5.4171x; 1.2980x over previous
//
#include <hip/hip_runtime.h>

#define EPS 1e-5f

constexpr int FIN = 22;   // input feature dim
constexpr int H   = 128;  // hidden dim

// bf16 helpers (bit-level, RN-even)
static __device__ __forceinline__ unsigned short f2bf(float f) {
    unsigned int u = __float_as_uint(f);
    unsigned int r = (u + 0x7fffu + ((u >> 16) & 1u)) >> 16;
    return (unsigned short)r;
}
static __device__ __forceinline__ float bf2f(unsigned short u) {
    return __uint_as_float(((unsigned int)u) << 16);
}

// ---------------- degree histogram ----------------
__global__ void deg_kernel(const int* __restrict__ ei, int* __restrict__ degi, int E) {
    int e = blockIdx.x * blockDim.x + threadIdx.x;
    if (e < E) atomicAdd(&degi[ei[E + e]], 1);
}

// ---------------- scan phase A: per-block exclusive scan + dinv + x->bf16 ----------------
__global__ __launch_bounds__(256) void scanA_kernel(
    const int* __restrict__ degi, const float* __restrict__ x,
    int* __restrict__ offs, int* __restrict__ bsum,
    float* __restrict__ dinv, unsigned short* __restrict__ xb, int N) {
    __shared__ int sh[256];
    const int t = threadIdx.x;
    const int i = blockIdx.x * 256 + t;
    int v = (i < N) ? degi[i] : 0;
    sh[t] = v;
    __syncthreads();
    int val = v;
    for (int off = 1; off < 256; off <<= 1) {
        int add = (t >= off) ? sh[t - off] : 0;
        __syncthreads();
        val += add;
        sh[t] = val;
        __syncthreads();
    }
    if (i < N) offs[i] = val - v;          // exclusive within block
    if (t == 255) bsum[blockIdx.x] = val;  // block total
    if (i < N) {
        dinv[i] = rsqrtf((float)v + 1.0f); // +1 self-loop
#pragma unroll
        for (int k = 0; k < FIN; ++k) xb[i * FIN + k] = f2bf(x[i * FIN + k]);
    }
}

// ---------------- scan phase B: exclusive scan of block sums ----------------
__global__ __launch_bounds__(256) void scanB_kernel(int* __restrict__ bsum, int nb) {
    __shared__ int sh[256];
    const int t = threadIdx.x;
    int v = (t < nb) ? bsum[t] : 0;
    sh[t] = v;
    __syncthreads();
    int val = v;
    for (int off = 1; off < 256; off <<= 1) {
        int add = (t >= off) ? sh[t - off] : 0;
        __syncthreads();
        val += add;
        sh[t] = val;
        __syncthreads();
    }
    if (t < nb) bsum[t] = val - v;
}

// ---------------- scan phase C: add block base ----------------
__global__ void scanC_kernel(int* __restrict__ offs, const int* __restrict__ bsum, int N) {
    int i = blockIdx.x * blockDim.x + threadIdx.x;
    if (i < N) offs[i] += bsum[blockIdx.x];
}

// ---------------- CSR fill; offs[d] shifts to end-of-range ----------------
__global__ void fill_kernel(const int* __restrict__ ei, const float* __restrict__ dinv,
                            int* __restrict__ offs, int* __restrict__ csrS,
                            float* __restrict__ csrN, int E) {
    int e = blockIdx.x * blockDim.x + threadIdx.x;
    if (e >= E) return;
    int s = ei[e], d = ei[E + e];
    int pos = atomicAdd(&offs[d], 1);
    csrS[pos] = s;
    csrN[pos] = dinv[s] * dinv[d];
}
// after fill: range of node d = [ d ? offs[d-1] : 0,  offs[d] )

// ---------------- layer-1 gather on bf16 x (22 feats) ----------------
__global__ void gather_x_kernel(const unsigned short* __restrict__ xb,
                                const float* __restrict__ dinv,
                                const int* __restrict__ offs, const int* __restrict__ csrS,
                                const float* __restrict__ csrN, float* __restrict__ xa, int N) {
    int t = blockIdx.x * blockDim.x + threadIdx.x;
    int node = t >> 5, k = t & 31;
    if (node >= N) return;
    int beg = node ? offs[node - 1] : 0;
    int end = offs[node];
    float di = dinv[node];
    float acc = 0.0f;
    if (k < FIN) acc = bf2f(xb[node * FIN + k]) * di * di;  // self-loop
    for (int e = beg; e < end; ++e) {
        int s = csrS[e];
        float w = csrN[e];
        if (k < FIN) acc += bf2f(xb[s * FIN + k]) * w;
    }
    if (k < FIN) xa[node * FIN + k] = acc;
}

// ---------------- gemm1: [N,22] @ [22,128], epilogue BN1(+b1)+ReLU ----------------
__global__ __launch_bounds__(256) void gemm1_kernel(
    const float* __restrict__ in, const float* __restrict__ W, float* __restrict__ h1,
    const float* __restrict__ b1, const float* __restrict__ mean1,
    const float* __restrict__ var1, const float* __restrict__ gamma1,
    const float* __restrict__ beta1, int N) {
    __shared__ float lds[16 * FIN];
    const int tid = threadIdx.x;
    const int m0  = blockIdx.x * 16;

    for (int idx = tid; idx < 16 * FIN; idx += 256) {
        int row = m0 + idx / FIN;
        lds[idx] = (row < N) ? in[m0 * FIN + idx] : 0.0f;
    }
    __syncthreads();

    const int f  = tid & 127;
    const int mg = tid >> 7;
    const float A = gamma1[f] * rsqrtf(var1[f] + EPS);
    const float B = (b1[f] - mean1[f]) * A + beta1[f];

    float acc[8];
#pragma unroll
    for (int j = 0; j < 8; ++j) acc[j] = 0.0f;
    for (int k = 0; k < FIN; ++k) {
        float w = W[k * H + f];
#pragma unroll
        for (int j = 0; j < 8; ++j) acc[j] += lds[(mg * 8 + j) * FIN + k] * w;
    }
#pragma unroll
    for (int j = 0; j < 8; ++j) {
        int node = m0 + mg * 8 + j;
        if (node < N) h1[node * H + f] = fmaxf(acc[j] * A + B, 0.0f);
    }
}

// ---------------- gemm2: [N,128] @ [128,128], epilogue *A2 -> bf16 ----------------
__global__ __launch_bounds__(256) void gemm2_kernel(
    const float* __restrict__ in, const float* __restrict__ W, unsigned short* __restrict__ h2b,
    const float* __restrict__ var2, const float* __restrict__ gamma2, int N) {
    __shared__ float lds[16 * H];
    const int tid = threadIdx.x;
    const int m0  = blockIdx.x * 16;

    for (int idx = tid; idx < 16 * H; idx += 256) {
        int row = m0 + idx / H;
        lds[idx] = (row < N) ? in[m0 * H + idx] : 0.0f;
    }
    __syncthreads();

    const int f  = tid & 127;
    const int mg = tid >> 7;
    const float A = gamma2[f] * rsqrtf(var2[f] + EPS);

    float acc[8];
#pragma unroll
    for (int j = 0; j < 8; ++j) acc[j] = 0.0f;
    for (int k = 0; k < H; ++k) {
        float w = W[k * H + f];
#pragma unroll
        for (int j = 0; j < 8; ++j) acc[j] += lds[(mg * 8 + j) * H + k] * w;
    }
#pragma unroll
    for (int j = 0; j < 8; ++j) {
        int node = m0 + mg * 8 + j;
        if (node < N) h2b[node * H + f] = f2bf(acc[j] * A);
    }
}

// ---------------- fused: layer-2 gather (bf16, A2 pre-folded) + BN2 + ReLU + FC + sigmoid ----------------
__global__ __launch_bounds__(256) void gfinal_kernel(
    const unsigned short* __restrict__ h2b, const float* __restrict__ dinv,
    const int* __restrict__ offs, const int* __restrict__ csrS, const float* __restrict__ csrN,
    const float* __restrict__ b2, const float* __restrict__ mean2,
    const float* __restrict__ var2, const float* __restrict__ gamma2,
    const float* __restrict__ beta2, const float* __restrict__ Wfc,
    const float* __restrict__ bfc, float* __restrict__ out, int N) {
    const int tid  = threadIdx.x;
    const int node = blockIdx.x * 4 + (tid >> 6);
    const int lane = tid & 63;
    if (node >= N) return;
    const int beg = node ? offs[node - 1] : 0;
    const int end = offs[node];
    const float di = dinv[node];
    const ushort2* h2v = reinterpret_cast<const ushort2*>(h2b);

    ushort2 sv = h2v[(size_t)node * 64 + lane];
    float w0 = di * di;
    float a0 = bf2f(sv.x) * w0;
    float a1 = bf2f(sv.y) * w0;
    for (int e = beg; e < end; ++e) {
        int s = csrS[e];
        float w = csrN[e];
        ushort2 hv = h2v[(size_t)s * 64 + lane];
        a0 += bf2f(hv.x) * w;
        a1 += bf2f(hv.y) * w;
    }
    const int f0 = lane * 2, f1 = f0 + 1;
    float A0 = gamma2[f0] * rsqrtf(var2[f0] + EPS);
    float B0 = (b2[f0] - mean2[f0]) * A0 + beta2[f0];
    float A1 = gamma2[f1] * rsqrtf(var2[f1] + EPS);
    float B1 = (b2[f1] - mean2[f1]) * A1 + beta2[f1];
    // acc already has A2 folded (h2b = h2*A2)
    float v0 = fmaxf(a0 + B0, 0.0f);
    float v1 = fmaxf(a1 + B1, 0.0f);
    float p = v0 * Wfc[f0] + v1 * Wfc[f1];
#pragma unroll
    for (int off = 32; off > 0; off >>= 1) p += __shfl_down(p, off);
    if (lane == 0) out[node] = 1.0f / (1.0f + expf(-(p + bfc[0])));
}

extern "C" void kernel_launch(void* const* d_in, const int* in_sizes, int n_in,
                              void* d_out, int out_size, void* d_ws, size_t ws_size,
                              hipStream_t stream) {
    const float* x      = (const float*)d_in[0];
    const int*   ei     = (const int*)d_in[1];
    const float* W1     = (const float*)d_in[2];
    const float* b1     = (const float*)d_in[3];
    const float* gamma1 = (const float*)d_in[4];
    const float* beta1  = (const float*)d_in[5];
    const float* mean1  = (const float*)d_in[6];
    const float* var1   = (const float*)d_in[7];
    const float* W2     = (const float*)d_in[8];
    const float* b2     = (const float*)d_in[9];
    const float* gamma2 = (const float*)d_in[10];
    const float* beta2  = (const float*)d_in[11];
    const float* mean2  = (const float*)d_in[12];
    const float* var2   = (const float*)d_in[13];
    const float* Wfc    = (const float*)d_in[14];
    const float* bfc    = (const float*)d_in[15];
    float* out = (float*)d_out;

    const int N = in_sizes[0] / FIN;   // 50000
    const int E = in_sizes[1] / 2;     // 800000
    const int NB = (N + 255) / 256;    // scan blocks

    // workspace layout (float/int = 4B units)
    int*   base = (int*)d_ws;
    int*   degi = base;                                   // N
    float* dinv = (float*)(base + N);                     // N
    int*   offs = base + 2 * (size_t)N;                   // N
    int*   bsum = base + 3 * (size_t)N;                   // 256
    int*   csrS = base + 3 * (size_t)N + 256;             // E
    float* csrN = (float*)(csrS + E);                     // E
    unsigned short* xb = (unsigned short*)(csrS + 2 * (size_t)E);     // N*22 ushort
    float* xa   = (float*)(csrS + 2 * (size_t)E + (size_t)N * FIN / 2); // N*22 f32
    float* h1   = xa + (size_t)N * FIN;                   // N*128 f32
    unsigned short* h2b = (unsigned short*)(h1 + (size_t)N * H);      // N*128 ushort

    hipMemsetAsync(degi, 0, (size_t)N * sizeof(int), stream);

    deg_kernel<<<(E + 255) / 256, 256, 0, stream>>>(ei, degi, E);
    scanA_kernel<<<NB, 256, 0, stream>>>(degi, x, offs, bsum, dinv, xb, N);
    scanB_kernel<<<1, 256, 0, stream>>>(bsum, NB);
    scanC_kernel<<<NB, 256, 0, stream>>>(offs, bsum, N);
    fill_kernel<<<(E + 255) / 256, 256, 0, stream>>>(ei, dinv, offs, csrS, csrN, E);

    // layer 1
    gather_x_kernel<<<((size_t)N * 32 + 255) / 256, 256, 0, stream>>>(
        xb, dinv, offs, csrS, csrN, xa, N);
    gemm1_kernel<<<(N + 15) / 16, 256, 0, stream>>>(
        xa, W1, h1, b1, mean1, var1, gamma1, beta1, N);

    // layer 2
    gemm2_kernel<<<(N + 15) / 16, 256, 0, stream>>>(h1, W2, h2b, var2, gamma2, N);

    // fused gather + BN2 + ReLU + FC + sigmoid
    gfinal_kernel<<<(N + 3) / 4, 256, 0, stream>>>(
        h2b, dinv, offs, csrS, csrN, b2, mean2, var2, gamma2, beta2, Wfc, bfc, out, N);
}

// Round 4
// 199.068 us; speedup vs baseline: 7.7677x; 1.4339x over previous
//
#include <hip/hip_runtime.h>

#define EPS 1e-5f

constexpr int FIN = 22;   // input feature dim
constexpr int XP  = 32;   // padded x feature stride
constexpr int H   = 128;  // hidden dim

// bf16 helpers (bit-level, RN-even)
static __device__ __forceinline__ unsigned short f2bf(float f) {
    unsigned int u = __float_as_uint(f);
    unsigned int r = (u + 0x7fffu + ((u >> 16) & 1u)) >> 16;
    return (unsigned short)r;
}
static __device__ __forceinline__ float bflo(unsigned int u) {  // low bf16 of a dword
    return __uint_as_float(u << 16);
}
static __device__ __forceinline__ float bfhi(unsigned int u) {  // high bf16 of a dword
    return __uint_as_float(u & 0xffff0000u);
}

// ---------------- degree histogram ----------------
__global__ void deg_kernel(const int* __restrict__ ei, int* __restrict__ degi, int E) {
    int e = blockIdx.x * blockDim.x + threadIdx.x;
    if (e < E) atomicAdd(&degi[ei[E + e]], 1);
}

// ---------------- BN constant prep: A=gamma*rsqrt(var+eps), B=(b-mean)*A+beta ----------------
__global__ void prep_kernel(const float* __restrict__ b1, const float* __restrict__ mean1,
                            const float* __restrict__ var1, const float* __restrict__ gamma1,
                            const float* __restrict__ beta1,
                            const float* __restrict__ b2, const float* __restrict__ mean2,
                            const float* __restrict__ var2, const float* __restrict__ gamma2,
                            const float* __restrict__ beta2,
                            float* __restrict__ A1f, float* __restrict__ B1f,
                            float* __restrict__ A2f, float* __restrict__ B2f) {
    int t = threadIdx.x;
    if (t < H) {
        float A1 = gamma1[t] * rsqrtf(var1[t] + EPS);
        A1f[t] = A1;
        B1f[t] = (b1[t] - mean1[t]) * A1 + beta1[t];
        float A2 = gamma2[t] * rsqrtf(var2[t] + EPS);
        A2f[t] = A2;
        B2f[t] = (b2[t] - mean2[t]) * A2 + beta2[t];
    }
}

// ---------------- scan phase A: per-block exclusive scan + dinv + x->bf16 (padded) ----------------
__global__ __launch_bounds__(256) void scanA_kernel(
    const int* __restrict__ degi, const float* __restrict__ x,
    int* __restrict__ offs, int* __restrict__ bsum,
    float* __restrict__ dinv, unsigned short* __restrict__ xb, int N) {
    __shared__ int sh[256];
    const int t = threadIdx.x;
    const int i = blockIdx.x * 256 + t;
    int v = (i < N) ? degi[i] : 0;
    sh[t] = v;
    __syncthreads();
    int val = v;
    for (int off = 1; off < 256; off <<= 1) {
        int add = (t >= off) ? sh[t - off] : 0;
        __syncthreads();
        val += add;
        sh[t] = val;
        __syncthreads();
    }
    if (i < N) offs[i] = val - v;          // exclusive within block
    if (t == 255) bsum[blockIdx.x] = val;  // block total
    if (i < N) {
        dinv[i] = rsqrtf((float)v + 1.0f); // +1 self-loop
#pragma unroll
        for (int k = 0; k < XP; ++k)
            xb[i * XP + k] = (k < FIN) ? f2bf(x[i * FIN + k]) : (unsigned short)0;
    }
}

// ---------------- scan phase B: exclusive scan of block sums ----------------
__global__ __launch_bounds__(256) void scanB_kernel(int* __restrict__ bsum, int nb) {
    __shared__ int sh[256];
    const int t = threadIdx.x;
    int v = (t < nb) ? bsum[t] : 0;
    sh[t] = v;
    __syncthreads();
    int val = v;
    for (int off = 1; off < 256; off <<= 1) {
        int add = (t >= off) ? sh[t - off] : 0;
        __syncthreads();
        val += add;
        sh[t] = val;
        __syncthreads();
    }
    if (t < nb) bsum[t] = val - v;
}

// ---------------- scan phase C: add block base ----------------
__global__ void scanC_kernel(int* __restrict__ offs, const int* __restrict__ bsum, int N) {
    int i = blockIdx.x * blockDim.x + threadIdx.x;
    if (i < N) offs[i] += bsum[blockIdx.x];
}

// ---------------- CSR fill (packed {src, norm}); offs[d] shifts to end-of-range ----------------
__global__ void fill_kernel(const int* __restrict__ ei, const float* __restrict__ dinv,
                            int* __restrict__ offs, int2* __restrict__ csrSN, int E) {
    int e = blockIdx.x * blockDim.x + threadIdx.x;
    if (e >= E) return;
    int s = ei[e], d = ei[E + e];
    int pos = atomicAdd(&offs[d], 1);
    csrSN[pos] = make_int2(s, __float_as_int(dinv[s] * dinv[d]));
}
// after fill: range of node d = [ d ? offs[d-1] : 0,  offs[d] )

// ---------------- layer-1 gather: wave=8 groups x 8 lanes, ushort4/lane ----------------
__global__ __launch_bounds__(256) void gather_x_kernel(
    const unsigned short* __restrict__ xb, const float* __restrict__ dinv,
    const int* __restrict__ offs, const int2* __restrict__ csrSN,
    float* __restrict__ xa, int N) {
    const int tid  = threadIdx.x;
    const int node = blockIdx.x * 4 + (tid >> 6);
    const int lane = tid & 63;
    if (node >= N) return;
    const int g  = lane >> 3;      // group 0..7
    const int fl = lane & 7;       // lane in group
    const int beg = node ? offs[node - 1] : 0;
    const int end = offs[node];

    float acc0 = 0.f, acc1 = 0.f, acc2 = 0.f, acc3 = 0.f;
    if (g == 0) {  // self-loop
        float di = dinv[node];
        float w = di * di;
        ushort4 v = *reinterpret_cast<const ushort4*>(xb + (size_t)node * XP + fl * 4);
        acc0 = bflo(v.x) * w; acc1 = bflo(v.y) * w;
        acc2 = bflo(v.z) * w; acc3 = bflo(v.w) * w;
    }
    for (int e = beg + g; e < end; e += 8) {
        int2 sw = csrSN[e];
        float w = __int_as_float(sw.y);
        ushort4 v = *reinterpret_cast<const ushort4*>(xb + (size_t)sw.x * XP + fl * 4);
        acc0 += bflo(v.x) * w; acc1 += bflo(v.y) * w;
        acc2 += bflo(v.z) * w; acc3 += bflo(v.w) * w;
    }
#pragma unroll
    for (int off = 8; off < 64; off <<= 1) {
        acc0 += __shfl_xor(acc0, off);
        acc1 += __shfl_xor(acc1, off);
        acc2 += __shfl_xor(acc2, off);
        acc3 += __shfl_xor(acc3, off);
    }
    if (g == 0) {
        float4 o = make_float4(acc0, acc1, acc2, acc3);
        *reinterpret_cast<float4*>(xa + (size_t)node * XP + fl * 4) = o;
    }
}

// ---------------- fused gemm1+BN1+ReLU+gemm2 (h1 stays in LDS) ----------------
__global__ __launch_bounds__(256) void gemm12_kernel(
    const float* __restrict__ xa, const float* __restrict__ W1, const float* __restrict__ W2,
    const float* __restrict__ A1f, const float* __restrict__ B1f, const float* __restrict__ A2f,
    unsigned short* __restrict__ h2b, int N) {
    __shared__ float lds1[16 * XP];        // xa tile
    __shared__ float lds2[H * 20];         // h1 tile, transposed [k][row], pad 20
    const int tid = threadIdx.x;
    const int m0  = blockIdx.x * 16;

    for (int idx = tid; idx < 16 * XP; idx += 256) {
        int row = m0 + (idx >> 5);
        lds1[idx] = (row < N) ? xa[(size_t)m0 * XP + idx] : 0.0f;
    }
    __syncthreads();

    const int f  = tid & 127;
    const int mg = tid >> 7;

    // gemm1: acc1[j] = h1_pre[row = mg*8+j][f]
    float acc1[8];
#pragma unroll
    for (int j = 0; j < 8; ++j) acc1[j] = 0.0f;
    for (int k = 0; k < FIN; ++k) {
        float w = W1[k * H + f];
#pragma unroll
        for (int j = 0; j < 8; ++j) acc1[j] += lds1[(mg * 8 + j) * XP + k] * w;
    }
    const float A1 = A1f[f], B1 = B1f[f];
    float4 h1a, h1b;
    h1a.x = fmaxf(acc1[0] * A1 + B1, 0.f); h1a.y = fmaxf(acc1[1] * A1 + B1, 0.f);
    h1a.z = fmaxf(acc1[2] * A1 + B1, 0.f); h1a.w = fmaxf(acc1[3] * A1 + B1, 0.f);
    h1b.x = fmaxf(acc1[4] * A1 + B1, 0.f); h1b.y = fmaxf(acc1[5] * A1 + B1, 0.f);
    h1b.z = fmaxf(acc1[6] * A1 + B1, 0.f); h1b.w = fmaxf(acc1[7] * A1 + B1, 0.f);
    *reinterpret_cast<float4*>(&lds2[f * 20 + mg * 8])     = h1a;
    *reinterpret_cast<float4*>(&lds2[f * 20 + mg * 8 + 4]) = h1b;
    __syncthreads();

    // gemm2: broadcast ds_read_b128 x2 per k
    float acc2[8];
#pragma unroll
    for (int j = 0; j < 8; ++j) acc2[j] = 0.0f;
    for (int k = 0; k < H; ++k) {
        float w = W2[k * H + f];
        float4 ha = *reinterpret_cast<const float4*>(&lds2[k * 20 + mg * 8]);
        float4 hb = *reinterpret_cast<const float4*>(&lds2[k * 20 + mg * 8 + 4]);
        acc2[0] += ha.x * w; acc2[1] += ha.y * w; acc2[2] += ha.z * w; acc2[3] += ha.w * w;
        acc2[4] += hb.x * w; acc2[5] += hb.y * w; acc2[6] += hb.z * w; acc2[7] += hb.w * w;
    }
    const float A2 = A2f[f];
#pragma unroll
    for (int j = 0; j < 8; ++j) {
        int node = m0 + mg * 8 + j;
        if (node < N) h2b[(size_t)node * H + f] = f2bf(acc2[j] * A2);
    }
}

// ---------------- fused: layer-2 gather + BN2 + ReLU + FC + sigmoid ----------------
// wave = 4 groups x 16 lanes; each lane: 8 features via one dwordx4
__global__ __launch_bounds__(256) void gfinal_kernel(
    const unsigned short* __restrict__ h2b, const float* __restrict__ dinv,
    const int* __restrict__ offs, const int2* __restrict__ csrSN,
    const float* __restrict__ B2f, const float* __restrict__ Wfc,
    const float* __restrict__ bfc, float* __restrict__ out, int N) {
    const int tid  = threadIdx.x;
    const int node = blockIdx.x * 4 + (tid >> 6);
    const int lane = tid & 63;
    if (node >= N) return;
    const int g  = lane >> 4;      // group 0..3
    const int fl = lane & 15;      // lane in group
    const int f0 = fl * 8;
    const int beg = node ? offs[node - 1] : 0;
    const int end = offs[node];

    float acc[8];
#pragma unroll
    for (int j = 0; j < 8; ++j) acc[j] = 0.0f;

    if (g == 0) {  // self-loop
        float di = dinv[node];
        float w = di * di;
        uint4 v = *reinterpret_cast<const uint4*>(h2b + (size_t)node * H + f0);
        acc[0] = bflo(v.x) * w; acc[1] = bfhi(v.x) * w;
        acc[2] = bflo(v.y) * w; acc[3] = bfhi(v.y) * w;
        acc[4] = bflo(v.z) * w; acc[5] = bfhi(v.z) * w;
        acc[6] = bflo(v.w) * w; acc[7] = bfhi(v.w) * w;
    }
    for (int e = beg + g; e < end; e += 4) {
        int2 sw = csrSN[e];
        float w = __int_as_float(sw.y);
        uint4 v = *reinterpret_cast<const uint4*>(h2b + (size_t)sw.x * H + f0);
        acc[0] += bflo(v.x) * w; acc[1] += bfhi(v.x) * w;
        acc[2] += bflo(v.y) * w; acc[3] += bfhi(v.y) * w;
        acc[4] += bflo(v.z) * w; acc[5] += bfhi(v.z) * w;
        acc[6] += bflo(v.w) * w; acc[7] += bfhi(v.w) * w;
    }
#pragma unroll
    for (int j = 0; j < 8; ++j) {
        acc[j] += __shfl_xor(acc[j], 16);
        acc[j] += __shfl_xor(acc[j], 32);
    }
    // BN2 shift (+B) + ReLU + FC partial (A2 pre-folded into h2b)
    float p = 0.0f;
#pragma unroll
    for (int j = 0; j < 8; ++j)
        p += fmaxf(acc[j] + B2f[f0 + j], 0.0f) * Wfc[f0 + j];
#pragma unroll
    for (int off = 1; off < 16; off <<= 1) p += __shfl_xor(p, off);
    if (lane == 0) out[node] = 1.0f / (1.0f + expf(-(p + bfc[0])));
}

static inline size_t align4w(size_t w) { return (w + 3) & ~(size_t)3; }  // 16B align (words)

extern "C" void kernel_launch(void* const* d_in, const int* in_sizes, int n_in,
                              void* d_out, int out_size, void* d_ws, size_t ws_size,
                              hipStream_t stream) {
    const float* x      = (const float*)d_in[0];
    const int*   ei     = (const int*)d_in[1];
    const float* W1     = (const float*)d_in[2];
    const float* b1     = (const float*)d_in[3];
    const float* gamma1 = (const float*)d_in[4];
    const float* beta1  = (const float*)d_in[5];
    const float* mean1  = (const float*)d_in[6];
    const float* var1   = (const float*)d_in[7];
    const float* W2     = (const float*)d_in[8];
    const float* b2     = (const float*)d_in[9];
    const float* gamma2 = (const float*)d_in[10];
    const float* beta2  = (const float*)d_in[11];
    const float* mean2  = (const float*)d_in[12];
    const float* var2   = (const float*)d_in[13];
    const float* Wfc    = (const float*)d_in[14];
    const float* bfc    = (const float*)d_in[15];
    float* out = (float*)d_out;

    const int N = in_sizes[0] / FIN;   // 50000
    const int E = in_sizes[1] / 2;     // 800000
    const int NB = (N + 255) / 256;

    // workspace layout (4-byte words, 16B-aligned sections)
    int* base = (int*)d_ws;
    size_t o = 0;
    int*   degi = base + o;                o = align4w(o + N);
    float* dinv = (float*)(base + o);      o = align4w(o + N);
    int*   offs = base + o;                o = align4w(o + N);
    int*   bsum = base + o;                o = align4w(o + 256);
    float* A1f  = (float*)(base + o);      o = align4w(o + H);
    float* B1f  = (float*)(base + o);      o = align4w(o + H);
    float* A2f  = (float*)(base + o);      o = align4w(o + H);
    float* B2f  = (float*)(base + o);      o = align4w(o + H);
    int2*  csrSN = (int2*)(base + o);      o = align4w(o + 2 * (size_t)E);
    unsigned short* xb = (unsigned short*)(base + o); o = align4w(o + (size_t)N * XP / 2);
    float* xa   = (float*)(base + o);      o = align4w(o + (size_t)N * XP);
    unsigned short* h2b = (unsigned short*)(base + o);

    hipMemsetAsync(degi, 0, (size_t)N * sizeof(int), stream);

    deg_kernel<<<(E + 255) / 256, 256, 0, stream>>>(ei, degi, E);
    prep_kernel<<<1, 128, 0, stream>>>(b1, mean1, var1, gamma1, beta1,
                                       b2, mean2, var2, gamma2, beta2,
                                       A1f, B1f, A2f, B2f);
    scanA_kernel<<<NB, 256, 0, stream>>>(degi, x, offs, bsum, dinv, xb, N);
    scanB_kernel<<<1, 256, 0, stream>>>(bsum, NB);
    scanC_kernel<<<NB, 256, 0, stream>>>(offs, bsum, N);
    fill_kernel<<<(E + 255) / 256, 256, 0, stream>>>(ei, dinv, offs, csrSN, E);

    gather_x_kernel<<<(N + 3) / 4, 256, 0, stream>>>(xb, dinv, offs, csrSN, xa, N);
    gemm12_kernel<<<(N + 15) / 16, 256, 0, stream>>>(xa, W1, W2, A1f, B1f, A2f, h2b, N);
    gfinal_kernel<<<(N + 3) / 4, 256, 0, stream>>>(h2b, dinv, offs, csrSN, B2f, Wfc, bfc, out, N);
}